// Round 4
// baseline (129.632 us; speedup 1.0000x reference)
//
#include <hip/hip_runtime.h>
#include <hip/hip_bf16.h>
#include <math.h>

#define BB 8
#define NN 1024
#define F_IN 384
#define F_HID 96
#define HEADS 8
#define F_OUT 384
#define ROWS (BB*NN)                 // 8192
#define H_DIM 1152                   // HEADS*F_HID + F_IN
#define OUT_DIM 1536                 // F_OUT + H_DIM
#define NEG 0.01f
#define LN_EPS 1e-5f
#define LOG2E 1.4426950408889634f

typedef __bf16 bf16x8 __attribute__((ext_vector_type(8)));
typedef float  f32x4  __attribute__((ext_vector_type(4)));

static __device__ __forceinline__ unsigned short b16u(float x) {
    union { __bf16 h; unsigned short u; } c; c.h = (__bf16)x; return c.u;
}

typedef __attribute__((address_space(1))) const unsigned char g1_t;
typedef __attribute__((address_space(3))) unsigned char l3_t;
static __device__ __forceinline__ void gl16(const void* g, void* l) {
    __builtin_amdgcn_global_load_lds((g1_t*)g, (l3_t*)l, 16, 0, 0);
}

// ---------------- kW: WmT[n][k] = bf16(Wm[k][n]) ----------------
__global__ __launch_bounds__(256) void kW(const float* __restrict__ Wm,
                                          unsigned short* __restrict__ WmT) {
    __shared__ float tile[32][33];
    const int t = threadIdx.x;
    const int k0 = (blockIdx.x / 12) * 32, n0 = (blockIdx.x % 12) * 32;
#pragma unroll
    for (int p = 0; p < 4; ++p) {
        const int e = t + 256*p, kk = e >> 5, nn = e & 31;
        tile[kk][nn] = Wm[(size_t)(k0 + kk) * F_OUT + n0 + nn];
    }
    __syncthreads();
#pragma unroll
    for (int p = 0; p < 4; ++p) {
        const int e = t + 256*p, nn = e >> 5, kk = e & 31;
        WmT[(size_t)(n0 + nn) * H_DIM + k0 + kk] = b16u(tile[kk][nn]);
    }
}

// ---------------- kA: LN(X) -> V -> VT bf16, Q, K (unchanged) ----------------
__global__ __launch_bounds__(256) void kA(const float* __restrict__ X,
                                          const float* __restrict__ Wv, const float* __restrict__ bv,
                                          const float* __restrict__ Wq, const float* __restrict__ bq,
                                          const float* __restrict__ Wk, const float* __restrict__ bk,
                                          unsigned short* __restrict__ VT,
                                          float* __restrict__ Qw, float* __restrict__ Kw) {
    __shared__ float xn[8][F_IN];
    __shared__ float vsh[8][F_HID];
    const int t = threadIdx.x, r = t >> 5, lane = t & 31;
    const int row0 = blockIdx.x * 8, row = row0 + r;
    const int b = row0 >> 10, i_in = row0 & 1023;

    const float4* xrow = (const float4*)(X + (size_t)row * F_IN);
    float4 xv[3];
    float s = 0.f, sq = 0.f;
#pragma unroll
    for (int k = 0; k < 3; ++k) {
        xv[k] = xrow[lane + 32*k];
        s  += xv[k].x + xv[k].y + xv[k].z + xv[k].w;
        sq += xv[k].x*xv[k].x + xv[k].y*xv[k].y + xv[k].z*xv[k].z + xv[k].w*xv[k].w;
    }
#pragma unroll
    for (int m = 1; m < 32; m <<= 1) { s += __shfl_xor(s, m); sq += __shfl_xor(sq, m); }
    const float mu  = s * (1.f/F_IN);
    const float var = sq * (1.f/F_IN) - mu*mu;
    const float rstd = rsqrtf(var + LN_EPS);
    float4* xnr = (float4*)xn[r];
#pragma unroll
    for (int k = 0; k < 3; ++k) {
        float4 o;
        o.x = (xv[k].x - mu) * rstd; o.y = (xv[k].y - mu) * rstd;
        o.z = (xv[k].z - mu) * rstd; o.w = (xv[k].w - mu) * rstd;
        xnr[lane + 32*k] = o;
    }
    __syncthreads();

    float acc[3];
#pragma unroll
    for (int c = 0; c < 3; ++c) acc[c] = bv[lane + 32*c];
    for (int f = 0; f < F_IN; ++f) {
        const float xvv = xn[r][f];
        const float* wrow = Wv + (size_t)f * F_HID + lane;
#pragma unroll
        for (int c = 0; c < 3; ++c) acc[c] = fmaf(xvv, wrow[32*c], acc[c]);
    }
#pragma unroll
    for (int c = 0; c < 3; ++c) vsh[r][lane + 32*c] = acc[c];
    __syncthreads();

#pragma unroll
    for (int p = 0; p < 3; ++p) {
        const int e = t + 256*p, f = e >> 3, ii = e & 7;
        VT[((size_t)b * F_HID + f) * NN + i_in + ii] = b16u(vsh[ii][f]);
    }

    if (t < 128) {
        const int rr = (t >> 3) & 7, h = t & 7;
        const bool isQ = (t < 64);
        const float* Wx = isQ ? Wq : Wk;
        float a = isQ ? bq[h] : bk[h];
#pragma unroll 8
        for (int j = 0; j < F_HID; ++j) a = fmaf(vsh[rr][j], Wx[j*HEADS + h], a);
        const size_t rowx = row0 + rr;
        if (isQ) Qw[rowx * HEADS + h] = a;
        else     Kw[rowx * HEADS + h] = a;
    }
}

// ---------------- kB: 8-wave MFMA attention + fused LN(H) ----------------
// 512 threads = 8 waves; wave w owns head w; 16 i-rows/block; chunk = 64 j
// grid = BB * NN/16 = 512 (2 blocks/CU, 4 waves/SIMD)
__global__ __launch_bounds__(512, 4) void kB(const float* __restrict__ X,
                                             const unsigned short* __restrict__ VT,
                                             const float* __restrict__ Qw,
                                             const float* __restrict__ Kw,
                                             float* __restrict__ out,
                                             unsigned short* __restrict__ Hn) {
    __shared__ float q_sh[16][8];                                  // 512 B
    __shared__ float k_sh[2][64][9];                               // 4.5 KB (pad 9)
    __shared__ __align__(16) unsigned short Wt[HEADS][16][64];     // 16 KB (swizzled)
    __shared__ __align__(16) unsigned short vt_sh[2][F_HID][64];   // 24 KB (swizzled, dbuf)
    __shared__ float lnS[8][16], lnQ2[8][16];
    __shared__ float sxS[16], sx2S[16];
    __shared__ float mu_sh[16], rs_sh[16];

    const int t = threadIdx.x;
    const int bid = (int)blockIdx.x;
    const int swz = (bid & 7) * 64 + (bid >> 3);   // bijective XCD swizzle (512%8==0)
    const int b  = swz >> 6;
    const int i0 = (swz & 63) * 16;
    const int w = t >> 6, l = t & 63, m = l & 15, g = l >> 4;
    const int si = t >> 5, sj = t & 31;            // softmax: row si, j-pair {2sj,2sj+1}

    const size_t vtbase = (size_t)b * F_HID * NN;
    const size_t krow   = (size_t)b * NN;

    if (t < 128) ((float*)q_sh)[t] = Qw[((size_t)(b*NN + i0)) * HEADS + t];

    // stage one 64-j V-tile: linear LDS dest, inverse-swizzled global source (rule 21)
#define STAGE_VT(buf, j0)                                                              \
    {                                                                                  \
        { const int f = t >> 3, c16 = t & 7;                                           \
          gl16(VT + vtbase + (size_t)f*NN + (j0) + (((c16 ^ (f&7))) << 3),             \
               (char*)vt_sh[buf] + t*16); }                                            \
        if (t < 256) {                                                                 \
          const int e = t + 512, f = e >> 3, c16 = e & 7;                              \
          gl16(VT + vtbase + (size_t)f*NN + (j0) + (((c16 ^ (f&7))) << 3),             \
               (char*)vt_sh[buf] + e*16); }                                            \
    }

    // prologue: stage chunk 0
    k_sh[0][t >> 3][t & 7] = Kw[(krow + (t >> 3)) * HEADS + (t & 7)];
    STAGE_VT(0, 0);
    __syncthreads();

    float q[8];
#pragma unroll
    for (int h = 0; h < 8; ++h) q[h] = q_sh[si][h] * LOG2E;   // fold log2e (lrelu commutes)

    const f32x4 z4 = {0.f, 0.f, 0.f, 0.f};
    f32x4 acc[6];
#pragma unroll
    for (int fb = 0; fb < 6; ++fb) acc[fb] = z4;

    unsigned int* WtU = (unsigned int*)Wt;

    for (int c = 0; c < 16; ++c) {
        const int cur = c & 1, nxt = cur ^ 1;
        const bool more = (c < 15);

        // issue next chunk's global loads early (land under softmax phase)
        float kreg = 0.f;
        if (more) {
            const int j0n = (c + 1) * 64;
            kreg = Kw[(krow + j0n + (t >> 3)) * HEADS + (t & 7)];
            STAGE_VT(nxt, j0n);
        }

        // softmax over heads for pairs (si, 2sj) and (si, 2sj+1)
        {
            const float2* kp0 = (const float2*)k_sh[cur][2*sj];
            const float2* kp1 = (const float2*)k_sh[cur][2*sj + 1];
            float kE[8], kO[8];
#pragma unroll
            for (int u = 0; u < 4; ++u) {
                const float2 a = kp0[u], bq2 = kp1[u];
                kE[2*u] = a.x; kE[2*u+1] = a.y; kO[2*u] = bq2.x; kO[2*u+1] = bq2.y;
            }
            float wE[8], wO[8];
            float sE = 0.f, sO = 0.f;
#pragma unroll
            for (int h = 0; h < 8; ++h) {
                float a0 = q[h] * kE[h]; a0 = fmaxf(a0, NEG*a0);
                float a1 = q[h] * kO[h]; a1 = fmaxf(a1, NEG*a1);
                wE[h] = __builtin_amdgcn_exp2f(a0); sE += wE[h];
                wO[h] = __builtin_amdgcn_exp2f(a1); sO += wO[h];
            }
            const float iE = __builtin_amdgcn_rcpf(sE);
            const float iO = __builtin_amdgcn_rcpf(sO);
            const int wbase = si*32 + (sj ^ ((si & 7) << 2));
#pragma unroll
            for (int h = 0; h < 8; ++h)
                WtU[h*512 + wbase] = (unsigned int)b16u(wE[h]*iE)
                                   | ((unsigned int)b16u(wO[h]*iO) << 16);
        }
        if (more) k_sh[nxt][t >> 3][t & 7] = kreg;
        __syncthreads();   // Wt + k_sh[nxt] visible; vmcnt drained -> vt_sh[nxt] ready

        // MFMA: head w, A = Wt[w] (16i x 64j), B = vt_sh[cur] (96f x 64j)
        bf16x8 af[2];
#pragma unroll
        for (int kh = 0; kh < 2; ++kh)
            af[kh] = *(const bf16x8*)((const char*)Wt + w*2048 + m*128
                                      + ((kh*64 + g*16) ^ ((m & 7) << 4)));
#pragma unroll
        for (int kh = 0; kh < 2; ++kh)
#pragma unroll
            for (int fb = 0; fb < 6; ++fb) {
                const int row = fb*16 + m;
                const bf16x8 bv_ = *(const bf16x8*)((const char*)vt_sh[cur] + row*128
                                                    + ((kh*64 + g*16) ^ ((m & 7) << 4)));
                acc[fb] = __builtin_amdgcn_mfma_f32_16x16x32_bf16(af[kh], bv_, acc[fb], 0, 0, 0);
            }
        __syncthreads();   // all waves done reading buf[cur] before it is re-staged
    }
#undef STAGE_VT

    // ---- fused LN(H): per-row sums from accs ----
    float s[4] = {0,0,0,0}, s2[4] = {0,0,0,0};
#pragma unroll
    for (int fb = 0; fb < 6; ++fb)
#pragma unroll
        for (int r = 0; r < 4; ++r) {
            const float v = acc[fb][r];
            s[r] += v; s2[r] += v*v;
        }
#pragma unroll
    for (int msk = 1; msk < 16; msk <<= 1)
#pragma unroll
        for (int r = 0; r < 4; ++r) {
            s[r]  += __shfl_xor(s[r],  msk);
            s2[r] += __shfl_xor(s2[r], msk);
        }
    if (m == 0) {
#pragma unroll
        for (int r = 0; r < 4; ++r) { lnS[w][g*4+r] = s[r]; lnQ2[w][g*4+r] = s2[r]; }
    }

    // X phase: 16 rows x 32 lanes, 3 float4 each
    const int rX = t >> 5, lX = t & 31;
    const size_t xrow = (size_t)(b*NN + i0 + rX);
    const float4* x4 = (const float4*)(X + xrow * F_IN);
    float4 xs[3];
    float sx = 0.f, sx2 = 0.f;
#pragma unroll
    for (int kk = 0; kk < 3; ++kk) {
        xs[kk] = x4[lX + 32*kk];
        sx  += xs[kk].x + xs[kk].y + xs[kk].z + xs[kk].w;
        sx2 += xs[kk].x*xs[kk].x + xs[kk].y*xs[kk].y + xs[kk].z*xs[kk].z + xs[kk].w*xs[kk].w;
    }
#pragma unroll
    for (int msk = 1; msk < 32; msk <<= 1) { sx += __shfl_xor(sx, msk); sx2 += __shfl_xor(sx2, msk); }
    if (lX == 0) { sxS[rX] = sx; sx2S[rX] = sx2; }
    __syncthreads();

    if (t < 16) {
        float tot = sxS[t], tot2 = sx2S[t];
#pragma unroll
        for (int ww = 0; ww < 8; ++ww) { tot += lnS[ww][t]; tot2 += lnQ2[ww][t]; }
        const float muh = tot * (1.f/H_DIM);
        const float varh = tot2 * (1.f/H_DIM) - muh*muh;
        mu_sh[t] = muh; rs_sh[t] = rsqrtf(varh + LN_EPS);
    }
    __syncthreads();

    // Hh: fp32 to out cols [384..1152), bf16-normalized to Hn cols [0..768)
#pragma unroll
    for (int r = 0; r < 4; ++r) {
        const int row = g*4 + r;
        const size_t orow = (size_t)(b*NN + i0 + row);
        const float muh = mu_sh[row], rs = rs_sh[row];
#pragma unroll
        for (int fb = 0; fb < 6; ++fb) {
            const int col = w*F_HID + fb*16 + m;
            const float v = acc[fb][r];
            out[orow * OUT_DIM + F_OUT + col] = v;
            Hn[orow * H_DIM + col] = b16u((v - muh) * rs);
        }
    }
    // X: fp32 passthrough to out cols [1152..1536), bf16-normalized to Hn cols [768..1152)
    {
        const float muh = mu_sh[rX], rs = rs_sh[rX];
        float4* oX = (float4*)(out + xrow * OUT_DIM + F_OUT + HEADS*F_HID);
#pragma unroll
        for (int kk = 0; kk < 3; ++kk) {
            oX[lX + 32*kk] = xs[kk];
            ushort4 hh;
            hh.x = b16u((xs[kk].x - muh) * rs);
            hh.y = b16u((xs[kk].y - muh) * rs);
            hh.z = b16u((xs[kk].z - muh) * rs);
            hh.w = b16u((xs[kk].w - muh) * rs);
            *(ushort4*)&Hn[xrow * H_DIM + HEADS*F_HID + 4*(lX + 32*kk)] = hh;
        }
    }
}

// ---------------- kC: O = lrelu(Hn @ WmT^T + bm), tiled MFMA GEMM ----------------
__global__ __launch_bounds__(256) void kC(const unsigned short* __restrict__ Hn,
                                          const unsigned short* __restrict__ WmT,
                                          const float* __restrict__ bm,
                                          float* __restrict__ out) {
    __shared__ __align__(16) unsigned short As[2][64*64];
    __shared__ __align__(16) unsigned short Bs[2][96*64];
    const int t = threadIdx.x, w = t >> 6, lane = t & 63, m = lane & 15, g = lane >> 4;
    const int bid = (int)blockIdx.x;
    const int swz = (bid & 7) * 64 + (bid >> 3);
    const int i0 = (swz >> 2) * 64;
    const int n0 = (swz & 3) * 96;
    const int wr = w >> 1, wc = w & 1;

    const f32x4 z4 = {0.f, 0.f, 0.f, 0.f};
    f32x4 acc[2][3];
#pragma unroll
    for (int ms = 0; ms < 2; ++ms)
#pragma unroll
        for (int ns = 0; ns < 3; ++ns) acc[ms][ns] = z4;

#define KC_STAGE(buf, k0)                                                              \
    {                                                                                  \
        _Pragma("unroll")                                                              \
        for (int p = 0; p < 2; ++p) {                                                  \
            const int e = t + 256*p, row = e >> 3, c16 = e & 7;                        \
            gl16(Hn + (size_t)(i0+row)*H_DIM + (k0) + ((c16 ^ (row&7)) << 3),          \
                 (char*)As[buf] + e*16);                                               \
        }                                                                              \
        _Pragma("unroll")                                                              \
        for (int p = 0; p < 3; ++p) {                                                  \
            const int e = t + 256*p, row = e >> 3, c16 = e & 7;                        \
            gl16(WmT + (size_t)(n0+row)*H_DIM + (k0) + ((c16 ^ (row&7)) << 3),         \
                 (char*)Bs[buf] + e*16);                                               \
        }                                                                              \
    }

    KC_STAGE(0, 0);
    __syncthreads();

    for (int s = 0; s < 18; ++s) {
        const int cur = s & 1;
        if (s < 17) KC_STAGE(cur ^ 1, (s + 1) * 64);
#pragma unroll
        for (int kh = 0; kh < 2; ++kh) {
            const int kb = kh*64 + g*16;
            bf16x8 af[2];
#pragma unroll
            for (int ms = 0; ms < 2; ++ms) {
                const int row = wr*32 + ms*16 + m;
                af[ms] = *(const bf16x8*)((const char*)As[cur] + row*128 + (kb ^ ((row&7)<<4)));
            }
#pragma unroll
            for (int ns = 0; ns < 3; ++ns) {
                const int row = wc*48 + ns*16 + m;
                const bf16x8 bf_ = *(const bf16x8*)((const char*)Bs[cur] + row*128 + (kb ^ ((row&7)<<4)));
                acc[0][ns] = __builtin_amdgcn_mfma_f32_16x16x32_bf16(af[0], bf_, acc[0][ns], 0, 0, 0);
                acc[1][ns] = __builtin_amdgcn_mfma_f32_16x16x32_bf16(af[1], bf_, acc[1][ns], 0, 0, 0);
            }
        }
        __syncthreads();
    }
#undef KC_STAGE

#pragma unroll
    for (int ms = 0; ms < 2; ++ms)
#pragma unroll
        for (int ns = 0; ns < 3; ++ns) {
            const int col = n0 + wc*48 + ns*16 + m;
            const float bmv = bm[col];
#pragma unroll
            for (int r = 0; r < 4; ++r) {
                float o = acc[ms][ns][r] + bmv;
                o = fmaxf(o, NEG * o);
                out[(size_t)(i0 + wr*32 + ms*16 + g*4 + r) * OUT_DIM + col] = o;
            }
        }
}

extern "C" void kernel_launch(void* const* d_in, const int* in_sizes, int n_in,
                              void* d_out, int out_size, void* d_ws, size_t ws_size,
                              hipStream_t stream) {
    const float* X  = (const float*)d_in[0];
    const float* Wv = (const float*)d_in[1];
    const float* bv = (const float*)d_in[2];
    const float* Wq = (const float*)d_in[3];
    const float* bq = (const float*)d_in[4];
    const float* Wk = (const float*)d_in[5];
    const float* bk = (const float*)d_in[6];
    const float* Wm = (const float*)d_in[7];
    const float* bm = (const float*)d_in[8];
    float* out = (float*)d_out;

    char* p = (char*)d_ws;
    unsigned short* VT  = (unsigned short*)p;                 p += (size_t)BB*F_HID*NN*2;
    float*          Qw  = (float*)p;                          p += (size_t)ROWS*HEADS*4;
    float*          Kw  = (float*)p;                          p += (size_t)ROWS*HEADS*4;
    unsigned short* WmT = (unsigned short*)p;                 p += (size_t)F_OUT*H_DIM*2;
    unsigned short* Hn  = (unsigned short*)p;
    (void)ws_size; (void)out_size; (void)n_in; (void)in_sizes;

    kW<<<(H_DIM/32)*(F_OUT/32), 256, 0, stream>>>(Wm, WmT);
    kA<<<ROWS/8, 256, 0, stream>>>(X, Wv, bv, Wq, bq, Wk, bk, VT, Qw, Kw);
    kB<<<BB*(NN/16), 512, 0, stream>>>(X, VT, Qw, Kw, out, Hn);
    kC<<<ROWS/64 * (F_OUT/96), 256, 0, stream>>>(Hn, WmT, bm, out);
}